// Round 10
// baseline (341.777 us; speedup 1.0000x reference)
//
#include <hip/hip_runtime.h>
#include <math.h>

constexpr int C = 20;   // classes
constexpr int M = 32;   // max GT per image
constexpr int GX = 128; // blocks per image (grid-stride over chunks)

struct Frag {
    float4 av;                  // anchor box
    float4 c0, c1, c2, c3, c4;  // 20 class probs
    float4 rv;                  // regression preds
};

__device__ __forceinline__ Frag load_frag(const float* __restrict__ cls,
                                          const float* __restrict__ reg,
                                          const float* __restrict__ anc,
                                          size_t bA, int a) {
    Frag f;
    f.av = *(const float4*)(anc + (size_t)a * 4);
    const float* cp = cls + (bA + (size_t)a) * C;
    f.c0 = *(const float4*)(cp + 0);
    f.c1 = *(const float4*)(cp + 4);
    f.c2 = *(const float4*)(cp + 8);
    f.c3 = *(const float4*)(cp + 12);
    f.c4 = *(const float4*)(cp + 16);
    f.rv = *(const float4*)(reg + (bA + (size_t)a) * 4);
    return f;
}

// d_ws layout: per image b: [b*4+0]=cls_sum, [b*4+1]=reg_sum, [b*4+2]=num_pos
__global__ __launch_bounds__(256, 4) void focal_main(
    const float* __restrict__ cls,   // [B,A,C]
    const float* __restrict__ reg,   // [B,A,4]
    const float* __restrict__ anc,   // [A,4]
    const float* __restrict__ ann,   // [B,M,5]
    float* __restrict__ ws,
    int A)
{
    __shared__ float4 s_gbox[M];   // {x1,y1,x2,y2}; invalid GT -> zero box (iou=0)
    __shared__ float  s_garea[M];
    __shared__ int    s_glbl[M];
    __shared__ float  s_red[4 * 3];

    const int b   = blockIdx.y;
    const int tid = threadIdx.x;
    const size_t bA = (size_t)b * A;
    const int nchunks = (A + 255) >> 8;

    // ---- stage annotations into LDS ONCE per block (validity folded in) ----
    if (tid < M) {
        const float* ap = ann + (size_t)b * M * 5 + (size_t)tid * 5;
        float x1 = ap[0], y1 = ap[1], x2 = ap[2], y2 = ap[3];
        const float lb = ap[4];
        s_glbl[tid] = (int)lb;
        if (lb == -1.0f) { x1 = 0.f; y1 = 0.f; x2 = 0.f; y2 = 0.f; }
        s_gbox[tid]  = make_float4(x1, y1, x2, y2);
        s_garea[tid] = (x2 - x1) * (y2 - y1);
    }
    __syncthreads();

    float clsAcc = 0.f, regAcc = 0.f, posAcc = 0.f;

    // ---- grid-stride over chunks with register double-buffered prefetch ----
    const int c0i = blockIdx.x;
    Frag cur;
    if (c0i < nchunks) {
        int a = c0i * 256 + tid; if (a >= A) a = A - 1;
        cur = load_frag(cls, reg, anc, bA, a);
    }
    for (int ch = c0i; ch < nchunks; ch += GX) {
        const bool has_next = (ch + GX) < nchunks;   // block-uniform
        Frag nxt;
        if (has_next) {
            int an = (ch + GX) * 256 + tid; if (an >= A) an = A - 1;
            nxt = load_frag(cls, reg, anc, bA, an);  // in flight during compute below
        }

        const int  a    = ch * 256 + tid;
        const bool live = a < A;

        const float4 av = cur.av;
        const float aw  = av.z - av.x;
        const float ah  = av.w - av.y;
        const float acx = av.x + 0.5f * aw;
        const float acy = av.y + 0.5f * ah;
        const float area_a = aw * ah;

        // ---- IoU max / argmax over M GT (2 broadcast LDS reads/iter) ----
        float bv = -1.0f;
        int   bi = 0;
        #pragma unroll
        for (int j = 0; j < M; ++j) {
            const float4 g  = s_gbox[j];
            const float  ab = s_garea[j];
            const float iw = fmaxf(fminf(av.z, g.z) - fmaxf(av.x, g.x), 0.f);
            const float ih = fmaxf(fminf(av.w, g.w) - fmaxf(av.y, g.y), 0.f);
            const float inter = iw * ih;
            const float ua = fmaxf(area_a + ab - inter, 1e-8f);
            const float iou = __fdividef(inter, ua);
            if (iou > bv) { bv = iou; bi = j; }   // first-occurrence argmax
        }

        const bool pos    = bv >= 0.5f;
        const bool ignore = (bv >= 0.4f) && !pos;
        const int  lbl    = s_glbl[bi];

        // ---- classification focal loss (branchless; masked at end) ----
        float pv[C];
        pv[0]=cur.c0.x;  pv[1]=cur.c0.y;  pv[2]=cur.c0.z;  pv[3]=cur.c0.w;
        pv[4]=cur.c1.x;  pv[5]=cur.c1.y;  pv[6]=cur.c1.z;  pv[7]=cur.c1.w;
        pv[8]=cur.c2.x;  pv[9]=cur.c2.y;  pv[10]=cur.c2.z; pv[11]=cur.c2.w;
        pv[12]=cur.c3.x; pv[13]=cur.c3.y; pv[14]=cur.c3.z; pv[15]=cur.c3.w;
        pv[16]=cur.c4.x; pv[17]=cur.c4.y; pv[18]=cur.c4.z; pv[19]=cur.c4.w;

        float clsSum = 0.f;
        #pragma unroll
        for (int c = 0; c < C; ++c) {
            const float p  = fminf(fmaxf(pv[c], 1e-8f), 1.0f - 1e-8f);
            const float q  = 1.0f - p;
            const bool  t1 = pos && (c == lbl);
            const float pe = t1 ? q : p;
            const float po = t1 ? p : q;
            const float w  = t1 ? 0.2f : 0.8f;
            // pe^1.5 == pe*sqrt(pe) exactly (gamma=1.5)
            clsSum += w * pe * __builtin_amdgcn_sqrtf(pe) * (-__logf(po));
        }
        clsAcc += (ignore || !live) ? 0.f : clsSum;

        // ---- regression smooth-L1 (positives only) ----
        if (pos && live) {
            posAcc += 1.f;
            const float4 g = s_gbox[bi];
            const float gwr = g.z - g.x, ghr = g.w - g.y;
            const float gcx = g.x + 0.5f * gwr, gcy = g.y + 0.5f * ghr;
            const float gw = fmaxf(gwr, 1.f), gh = fmaxf(ghr, 1.f);
            float rt[4];
            rt[0] = ((gcx - acx) / aw) / 0.1f;
            rt[1] = ((gcy - acy) / ah) / 0.1f;
            rt[2] = __logf(gw / aw) / 0.2f;
            rt[3] = __logf(gh / ah) / 0.2f;
            const float rr[4] = {cur.rv.x, cur.rv.y, cur.rv.z, cur.rv.w};
            #pragma unroll
            for (int u = 0; u < 4; ++u) {
                const float d = fabsf(rt[u] - rr[u]);
                regAcc += (d <= (float)(1.0 / 9.0)) ? (4.5f * d * d)
                                                    : (d - (float)(0.5 / 9.0));
            }
        }

        if (has_next) cur = nxt;   // waitcnt for the prefetch lands HERE
    }

    // ---- block reduce once: wave shuffle -> cross-wave LDS -> 3 atomics ----
    #pragma unroll
    for (int off = 32; off > 0; off >>= 1) {
        clsAcc += __shfl_down(clsAcc, off, 64);
        regAcc += __shfl_down(regAcc, off, 64);
        posAcc += __shfl_down(posAcc, off, 64);
    }
    const int wave = tid >> 6;
    const int lane = tid & 63;
    if (lane == 0) {
        s_red[wave * 3 + 0] = clsAcc;
        s_red[wave * 3 + 1] = regAcc;
        s_red[wave * 3 + 2] = posAcc;
    }
    __syncthreads();
    if (tid == 0) {
        float cs = 0.f, rs = 0.f, ps = 0.f;
        #pragma unroll
        for (int w2 = 0; w2 < 4; ++w2) {
            cs += s_red[w2 * 3 + 0];
            rs += s_red[w2 * 3 + 1];
            ps += s_red[w2 * 3 + 2];
        }
        atomicAdd(&ws[b * 4 + 0], cs);
        atomicAdd(&ws[b * 4 + 1], rs);
        atomicAdd(&ws[b * 4 + 2], ps);
    }
}

// Finalize: 256 threads load all (b,gt) validity flags in parallel.
__global__ __launch_bounds__(256) void focal_final(
    const float* __restrict__ ws,
    const float* __restrict__ ann,
    float* __restrict__ out, int B)
{
    __shared__ float s_f[256];
    __shared__ float s_c[8], s_r[8];
    const int tid = threadIdx.x;

    float f = 0.f;
    if (tid < B * M) {
        const int bb = tid >> 5, j = tid & 31;
        f = (ann[(size_t)bb * M * 5 + (size_t)j * 5 + 4] != -1.0f) ? 1.f : 0.f;
    }
    s_f[tid] = f;
    __syncthreads();

    if (tid < B) {
        float nv = 0.f;
        #pragma unroll
        for (int j = 0; j < M; ++j) nv += s_f[tid * M + j];
        const float S  = ws[tid * 4 + 0];
        const float R  = ws[tid * 4 + 1];
        const float np = ws[tid * 4 + 2];
        float cl = S / fmaxf(np, 1.f);
        float rl = (np > 0.f) ? R / fmaxf(4.f * np, 1.f) : 0.f;
        if (nv == 0.f) { cl = 0.f; rl = 0.f; }
        s_c[tid] = cl; s_r[tid] = rl;
    }
    __syncthreads();

    if (tid == 0) {
        float ca = 0.f, ra = 0.f;
        for (int b2 = 0; b2 < B; ++b2) { ca += s_c[b2]; ra += s_r[b2]; }
        out[0] = ca / (float)B;
        out[1] = ra / (float)B;
    }
}

extern "C" void kernel_launch(void* const* d_in, const int* in_sizes, int n_in,
                              void* d_out, int out_size, void* d_ws, size_t ws_size,
                              hipStream_t stream) {
    const float* cls = (const float*)d_in[0];   // [B,A,C]
    const float* reg = (const float*)d_in[1];   // [B,A,4]
    const float* anc = (const float*)d_in[2];   // [1,A,4]
    const float* ann = (const float*)d_in[3];   // [B,M,5]
    const int A = in_sizes[2] / 4;
    const int B = in_sizes[3] / (M * 5);
    float* ws = (float*)d_ws;

    // d_ws is re-poisoned to 0xAA before every launch — zero the accumulators.
    hipMemsetAsync(d_ws, 0, (size_t)B * 4 * sizeof(float), stream);

    dim3 grid(GX, B);
    focal_main<<<grid, dim3(256), 0, stream>>>(cls, reg, anc, ann, ws, A);
    focal_final<<<1, dim3(256), 0, stream>>>(ws, ann, (float*)d_out, B);
}

// Round 11
// 291.668 us; speedup vs baseline: 1.1718x; 1.1718x over previous
//
#include <hip/hip_runtime.h>
#include <math.h>

constexpr int C = 20;   // classes
constexpr int M = 32;   // max GT per image
constexpr int GX = 128; // blocks per image (grid-stride over 256-anchor chunks)

// d_ws layout: per image b: [b*4+0]=cls_sum, [b*4+1]=reg_sum, [b*4+2]=num_pos
__global__ __launch_bounds__(256, 4) void focal_main(
    const float* __restrict__ cls,   // [B,A,C]
    const float* __restrict__ reg,   // [B,A,4]
    const float* __restrict__ anc,   // [A,4]
    const float* __restrict__ ann,   // [B,M,5]
    float* __restrict__ ws,
    int A)
{
    __shared__ float4 s_gbox[M];   // {x1,y1,x2,y2}; invalid GT -> zero box (iou=0)
    __shared__ float  s_garea[M];
    __shared__ int    s_glbl[M];
    __shared__ float  s_red[4 * 3];

    const int b   = blockIdx.y;
    const int tid = threadIdx.x;
    const size_t bA = (size_t)b * A;
    const int nchunks = (A + 255) >> 8;   // 469 for A=120000; GX=128 <= nchunks

    // ---- stage annotations into LDS once per block (validity folded in) ----
    if (tid < M) {
        const float* ap = ann + (size_t)b * M * 5 + (size_t)tid * 5;
        float x1 = ap[0], y1 = ap[1], x2 = ap[2], y2 = ap[3];
        const float lb = ap[4];
        s_glbl[tid] = (int)lb;
        if (lb == -1.0f) { x1 = 0.f; y1 = 0.f; x2 = 0.f; y2 = 0.f; }
        s_gbox[tid]  = make_float4(x1, y1, x2, y2);
        s_garea[tid] = (x2 - x1) * (y2 - y1);
    }
    __syncthreads();

    float clsAcc = 0.f, regAcc = 0.f, posAcc = 0.f;

    // ---- grid-stride pipeline; buffers are NAMED float4s, loads/rotation
    //      UNCONDITIONAL so nothing can be demoted to scratch (R10 lesson:
    //      conditional struct prefetch spilled -> 309 MB scratch writes). ----
    {
        int a0 = blockIdx.x * 256 + tid; if (a0 >= A) a0 = A - 1;
        const float* cp0 = cls + (bA + (size_t)a0) * C;
        float4 cv_av = *(const float4*)(anc + (size_t)a0 * 4);
        float4 cv_c0 = *(const float4*)(cp0 + 0);
        float4 cv_c1 = *(const float4*)(cp0 + 4);
        float4 cv_c2 = *(const float4*)(cp0 + 8);
        float4 cv_c3 = *(const float4*)(cp0 + 12);
        float4 cv_c4 = *(const float4*)(cp0 + 16);
        float4 cv_rv = *(const float4*)(reg + (bA + (size_t)a0) * 4);

        for (int ch = blockIdx.x; ch < nchunks; ch += GX) {
            // prefetch chunk ch+GX (clamped: last iter re-reads same, L1-hot)
            const int chn = (ch + GX < nchunks) ? (ch + GX) : ch;
            int an = chn * 256 + tid; if (an >= A) an = A - 1;
            const float* cpn = cls + (bA + (size_t)an) * C;
            const float4 nx_av = *(const float4*)(anc + (size_t)an * 4);
            const float4 nx_c0 = *(const float4*)(cpn + 0);
            const float4 nx_c1 = *(const float4*)(cpn + 4);
            const float4 nx_c2 = *(const float4*)(cpn + 8);
            const float4 nx_c3 = *(const float4*)(cpn + 12);
            const float4 nx_c4 = *(const float4*)(cpn + 16);
            const float4 nx_rv = *(const float4*)(reg + (bA + (size_t)an) * 4);

            const int  a    = ch * 256 + tid;
            const bool live = a < A;

            const float4 av = cv_av;
            const float aw  = av.z - av.x;
            const float ah  = av.w - av.y;
            const float acx = av.x + 0.5f * aw;
            const float acy = av.y + 0.5f * ah;
            const float area_a = aw * ah;

            // ---- IoU max / argmax over M GT (2 broadcast LDS reads/iter) ----
            float bv = -1.0f;
            int   bi = 0;
            #pragma unroll
            for (int j = 0; j < M; ++j) {
                const float4 g  = s_gbox[j];
                const float  ab = s_garea[j];
                const float iw = fmaxf(fminf(av.z, g.z) - fmaxf(av.x, g.x), 0.f);
                const float ih = fmaxf(fminf(av.w, g.w) - fmaxf(av.y, g.y), 0.f);
                const float inter = iw * ih;
                const float ua = fmaxf(area_a + ab - inter, 1e-8f);
                const float iou = __fdividef(inter, ua);
                if (iou > bv) { bv = iou; bi = j; }   // first-occurrence argmax
            }

            const bool pos    = bv >= 0.5f;
            const bool ignore = (bv >= 0.4f) && !pos;
            const int  lbl    = s_glbl[bi];

            // ---- classification focal loss (branchless; masked at end) ----
            float pv[C];
            pv[0]=cv_c0.x;  pv[1]=cv_c0.y;  pv[2]=cv_c0.z;  pv[3]=cv_c0.w;
            pv[4]=cv_c1.x;  pv[5]=cv_c1.y;  pv[6]=cv_c1.z;  pv[7]=cv_c1.w;
            pv[8]=cv_c2.x;  pv[9]=cv_c2.y;  pv[10]=cv_c2.z; pv[11]=cv_c2.w;
            pv[12]=cv_c3.x; pv[13]=cv_c3.y; pv[14]=cv_c3.z; pv[15]=cv_c3.w;
            pv[16]=cv_c4.x; pv[17]=cv_c4.y; pv[18]=cv_c4.z; pv[19]=cv_c4.w;

            float clsSum = 0.f;
            #pragma unroll
            for (int c = 0; c < C; ++c) {
                const float p  = fminf(fmaxf(pv[c], 1e-8f), 1.0f - 1e-8f);
                const float q  = 1.0f - p;
                const bool  t1 = pos && (c == lbl);
                const float pe = t1 ? q : p;
                const float po = t1 ? p : q;
                const float w  = t1 ? 0.2f : 0.8f;
                // pe^1.5 == pe*sqrt(pe) exactly (gamma=1.5)
                clsSum += w * pe * __builtin_amdgcn_sqrtf(pe) * (-__logf(po));
            }
            clsAcc += (ignore || !live) ? 0.f : clsSum;

            // ---- regression smooth-L1 (positives only) ----
            if (pos && live) {
                posAcc += 1.f;
                const float4 g = s_gbox[bi];
                const float gwr = g.z - g.x, ghr = g.w - g.y;
                const float gcx = g.x + 0.5f * gwr, gcy = g.y + 0.5f * ghr;
                const float gw = fmaxf(gwr, 1.f), gh = fmaxf(ghr, 1.f);
                float rt[4];
                rt[0] = ((gcx - acx) / aw) / 0.1f;
                rt[1] = ((gcy - acy) / ah) / 0.1f;
                rt[2] = __logf(gw / aw) / 0.2f;
                rt[3] = __logf(gh / ah) / 0.2f;
                const float rr[4] = {cv_rv.x, cv_rv.y, cv_rv.z, cv_rv.w};
                #pragma unroll
                for (int u = 0; u < 4; ++u) {
                    const float d = fabsf(rt[u] - rr[u]);
                    regAcc += (d <= (float)(1.0 / 9.0)) ? (4.5f * d * d)
                                                        : (d - (float)(0.5 / 9.0));
                }
            }

            // unconditional rotation — waitcnt for the prefetch lands here
            cv_av = nx_av;
            cv_c0 = nx_c0; cv_c1 = nx_c1; cv_c2 = nx_c2;
            cv_c3 = nx_c3; cv_c4 = nx_c4;
            cv_rv = nx_rv;
        }
    }

    // ---- block reduce once: wave shuffle -> cross-wave LDS -> 3 atomics ----
    #pragma unroll
    for (int off = 32; off > 0; off >>= 1) {
        clsAcc += __shfl_down(clsAcc, off, 64);
        regAcc += __shfl_down(regAcc, off, 64);
        posAcc += __shfl_down(posAcc, off, 64);
    }
    const int wave = tid >> 6;
    const int lane = tid & 63;
    if (lane == 0) {
        s_red[wave * 3 + 0] = clsAcc;
        s_red[wave * 3 + 1] = regAcc;
        s_red[wave * 3 + 2] = posAcc;
    }
    __syncthreads();
    if (tid == 0) {
        float cs = 0.f, rs = 0.f, ps = 0.f;
        #pragma unroll
        for (int w2 = 0; w2 < 4; ++w2) {
            cs += s_red[w2 * 3 + 0];
            rs += s_red[w2 * 3 + 1];
            ps += s_red[w2 * 3 + 2];
        }
        atomicAdd(&ws[b * 4 + 0], cs);
        atomicAdd(&ws[b * 4 + 1], rs);
        atomicAdd(&ws[b * 4 + 2], ps);
    }
}

// Finalize: 256 threads load all (b,gt) validity flags in parallel.
__global__ __launch_bounds__(256) void focal_final(
    const float* __restrict__ ws,
    const float* __restrict__ ann,
    float* __restrict__ out, int B)
{
    __shared__ float s_f[256];
    __shared__ float s_c[8], s_r[8];
    const int tid = threadIdx.x;

    float f = 0.f;
    if (tid < B * M) {
        const int bb = tid >> 5, j = tid & 31;
        f = (ann[(size_t)bb * M * 5 + (size_t)j * 5 + 4] != -1.0f) ? 1.f : 0.f;
    }
    s_f[tid] = f;
    __syncthreads();

    if (tid < B) {
        float nv = 0.f;
        #pragma unroll
        for (int j = 0; j < M; ++j) nv += s_f[tid * M + j];
        const float S  = ws[tid * 4 + 0];
        const float R  = ws[tid * 4 + 1];
        const float np = ws[tid * 4 + 2];
        float cl = S / fmaxf(np, 1.f);
        float rl = (np > 0.f) ? R / fmaxf(4.f * np, 1.f) : 0.f;
        if (nv == 0.f) { cl = 0.f; rl = 0.f; }
        s_c[tid] = cl; s_r[tid] = rl;
    }
    __syncthreads();

    if (tid == 0) {
        float ca = 0.f, ra = 0.f;
        for (int b2 = 0; b2 < B; ++b2) { ca += s_c[b2]; ra += s_r[b2]; }
        out[0] = ca / (float)B;
        out[1] = ra / (float)B;
    }
}

extern "C" void kernel_launch(void* const* d_in, const int* in_sizes, int n_in,
                              void* d_out, int out_size, void* d_ws, size_t ws_size,
                              hipStream_t stream) {
    const float* cls = (const float*)d_in[0];   // [B,A,C]
    const float* reg = (const float*)d_in[1];   // [B,A,4]
    const float* anc = (const float*)d_in[2];   // [1,A,4]
    const float* ann = (const float*)d_in[3];   // [B,M,5]
    const int A = in_sizes[2] / 4;
    const int B = in_sizes[3] / (M * 5);
    float* ws = (float*)d_ws;

    // d_ws is re-poisoned to 0xAA before every launch — zero the accumulators.
    hipMemsetAsync(d_ws, 0, (size_t)B * 4 * sizeof(float), stream);

    dim3 grid(GX, B);
    focal_main<<<grid, dim3(256), 0, stream>>>(cls, reg, anc, ann, ws, A);
    focal_final<<<1, dim3(256), 0, stream>>>(ws, ann, (float*)d_out, B);
}

// Round 12
// 231.625 us; speedup vs baseline: 1.4756x; 1.2592x over previous
//
#include <hip/hip_runtime.h>
#include <math.h>

constexpr int C = 20;   // classes
constexpr int M = 32;   // max GT per image

constexpr int TAG_IGNORE = 254;
constexpr int TAG_NEG    = 255;
constexpr size_t TAG_OFF = 1024;   // tags live at d_ws + 1KB; accumulators at 0

// ---------------------------------------------------------------------------
// Kernel 1: IoU/argmax -> 1-byte tag per (b,anchor); reg smooth-L1 + num_pos.
// Reads: anchors (L2-resident), annotations, reg (positives only).
// ---------------------------------------------------------------------------
__global__ __launch_bounds__(256) void focal_assign(
    const float* __restrict__ reg,   // [B,A,4]
    const float* __restrict__ anc,   // [A,4]
    const float* __restrict__ ann,   // [B,M,5]
    unsigned char* __restrict__ tags,// [B,A]
    float* __restrict__ ws,
    int A)
{
    __shared__ float4 s_gbox[M];   // invalid GT -> zero box (iou=0)
    __shared__ float  s_garea[M];
    __shared__ int    s_glbl[M];
    __shared__ float  s_red[4 * 2];

    const int b   = blockIdx.y;
    const int tid = threadIdx.x;
    const int a   = blockIdx.x * 256 + tid;
    const size_t bA = (size_t)b * A;

    if (tid < M) {
        const float* ap = ann + (size_t)b * M * 5 + (size_t)tid * 5;
        float x1 = ap[0], y1 = ap[1], x2 = ap[2], y2 = ap[3];
        const float lb = ap[4];
        s_glbl[tid] = (int)lb;
        if (lb == -1.0f) { x1 = 0.f; y1 = 0.f; x2 = 0.f; y2 = 0.f; }
        s_gbox[tid]  = make_float4(x1, y1, x2, y2);
        s_garea[tid] = (x2 - x1) * (y2 - y1);
    }
    __syncthreads();

    float regAcc = 0.f, posAcc = 0.f;

    if (a < A) {
        const float4 av = *(const float4*)(anc + (size_t)a * 4);
        const float aw  = av.z - av.x;
        const float ah  = av.w - av.y;
        const float acx = av.x + 0.5f * aw;
        const float acy = av.y + 0.5f * ah;
        const float area_a = aw * ah;

        // IoU max / argmax over M GT (2 broadcast LDS reads/iter)
        float bv = -1.0f;
        int   bi = 0;
        #pragma unroll
        for (int j = 0; j < M; ++j) {
            const float4 g  = s_gbox[j];
            const float  ab = s_garea[j];
            const float iw = fmaxf(fminf(av.z, g.z) - fmaxf(av.x, g.x), 0.f);
            const float ih = fmaxf(fminf(av.w, g.w) - fmaxf(av.y, g.y), 0.f);
            const float inter = iw * ih;
            const float ua = fmaxf(area_a + ab - inter, 1e-8f);
            const float iou = __fdividef(inter, ua);
            if (iou > bv) { bv = iou; bi = j; }   // first-occurrence argmax
        }

        const bool pos    = bv >= 0.5f;
        const bool ignore = (bv >= 0.4f) && !pos;

        int tag = TAG_NEG;
        if (ignore) tag = TAG_IGNORE;
        if (pos)    tag = s_glbl[bi];            // 0..19 (iou>=0.5 => valid GT)
        tags[bA + a] = (unsigned char)tag;

        if (pos) {
            posAcc = 1.f;
            const float4 g = s_gbox[bi];
            const float gwr = g.z - g.x, ghr = g.w - g.y;
            const float gcx = g.x + 0.5f * gwr, gcy = g.y + 0.5f * ghr;
            const float gw = fmaxf(gwr, 1.f), gh = fmaxf(ghr, 1.f);
            float rt[4];
            rt[0] = ((gcx - acx) / aw) / 0.1f;
            rt[1] = ((gcy - acy) / ah) / 0.1f;
            rt[2] = __logf(gw / aw) / 0.2f;
            rt[3] = __logf(gh / ah) / 0.2f;
            const float4 rv = *(const float4*)(reg + (bA + (size_t)a) * 4);
            const float rr[4] = {rv.x, rv.y, rv.z, rv.w};
            #pragma unroll
            for (int u = 0; u < 4; ++u) {
                const float d = fabsf(rt[u] - rr[u]);
                regAcc += (d <= (float)(1.0 / 9.0)) ? (4.5f * d * d)
                                                    : (d - (float)(0.5 / 9.0));
            }
        }
    }

    #pragma unroll
    for (int off = 32; off > 0; off >>= 1) {
        regAcc += __shfl_down(regAcc, off, 64);
        posAcc += __shfl_down(posAcc, off, 64);
    }
    const int wave = tid >> 6, lane = tid & 63;
    if (lane == 0) { s_red[wave*2+0] = regAcc; s_red[wave*2+1] = posAcc; }
    __syncthreads();
    if (tid == 0) {
        float rs = 0.f, ps = 0.f;
        #pragma unroll
        for (int w2 = 0; w2 < 4; ++w2) { rs += s_red[w2*2+0]; ps += s_red[w2*2+1]; }
        atomicAdd(&ws[b*4+1], rs);
        atomicAdd(&ws[b*4+2], ps);
    }
}

// ---------------------------------------------------------------------------
// Kernel 2: pure streaming focal loss. 80B cls + 1B tag per anchor.
// Sum negative-form term for all classes; correct the label class for pos.
// ---------------------------------------------------------------------------
__global__ __launch_bounds__(256) void focal_cls(
    const float* __restrict__ cls,   // [B,A,C]
    const unsigned char* __restrict__ tags,
    float* __restrict__ ws,
    int A)
{
    __shared__ float s_red[4];

    const int b   = blockIdx.y;
    const int tid = threadIdx.x;
    const int a   = blockIdx.x * 256 + tid;
    const size_t bA = (size_t)b * A;

    float clsSum = 0.f;

    if (a < A) {
        const int tag = tags[bA + a];
        const float* cp = cls + (bA + (size_t)a) * C;
        const float4 c0 = *(const float4*)(cp + 0);
        const float4 c1 = *(const float4*)(cp + 4);
        const float4 c2 = *(const float4*)(cp + 8);
        const float4 c3 = *(const float4*)(cp + 12);
        const float4 c4 = *(const float4*)(cp + 16);

        float pv[C];
        pv[0]=c0.x;  pv[1]=c0.y;  pv[2]=c0.z;  pv[3]=c0.w;
        pv[4]=c1.x;  pv[5]=c1.y;  pv[6]=c1.z;  pv[7]=c1.w;
        pv[8]=c2.x;  pv[9]=c2.y;  pv[10]=c2.z; pv[11]=c2.w;
        pv[12]=c3.x; pv[13]=c3.y; pv[14]=c3.z; pv[15]=c3.w;
        pv[16]=c4.x; pv[17]=c4.y; pv[18]=c4.z; pv[19]=c4.w;

        float sum = 0.f;
        float p_t = 0.5f;                       // label-class prob (pos only)
        #pragma unroll
        for (int c = 0; c < C; ++c) {
            const float p = fminf(fmaxf(pv[c], 1e-8f), 1.0f - 1e-8f);
            // negative-form focal term: 0.8 * p^1.5 * (-log(1-p)); p^1.5 exact
            sum += 0.8f * p * __builtin_amdgcn_sqrtf(p) * (-__logf(1.0f - p));
            p_t = (c == tag) ? p : p_t;         // one cndmask per class
        }
        if (tag < C) {                          // positive: swap label term
            const float q = 1.0f - p_t;
            sum -= 0.8f * p_t * __builtin_amdgcn_sqrtf(p_t) * (-__logf(q));
            sum += 0.2f * q   * __builtin_amdgcn_sqrtf(q)   * (-__logf(p_t));
        }
        clsSum = (tag == TAG_IGNORE) ? 0.f : sum;
    }

    #pragma unroll
    for (int off = 32; off > 0; off >>= 1)
        clsSum += __shfl_down(clsSum, off, 64);
    const int wave = tid >> 6, lane = tid & 63;
    if (lane == 0) s_red[wave] = clsSum;
    __syncthreads();
    if (tid == 0)
        atomicAdd(&ws[b*4+0], s_red[0] + s_red[1] + s_red[2] + s_red[3]);
}

// Finalize: 256 threads load all (b,gt) validity flags in parallel.
__global__ __launch_bounds__(256) void focal_final(
    const float* __restrict__ ws,
    const float* __restrict__ ann,
    float* __restrict__ out, int B)
{
    __shared__ float s_f[256];
    __shared__ float s_c[8], s_r[8];
    const int tid = threadIdx.x;

    float f = 0.f;
    if (tid < B * M) {
        const int bb = tid >> 5, j = tid & 31;
        f = (ann[(size_t)bb * M * 5 + (size_t)j * 5 + 4] != -1.0f) ? 1.f : 0.f;
    }
    s_f[tid] = f;
    __syncthreads();

    if (tid < B) {
        float nv = 0.f;
        #pragma unroll
        for (int j = 0; j < M; ++j) nv += s_f[tid * M + j];
        const float S  = ws[tid * 4 + 0];
        const float R  = ws[tid * 4 + 1];
        const float np = ws[tid * 4 + 2];
        float cl = S / fmaxf(np, 1.f);
        float rl = (np > 0.f) ? R / fmaxf(4.f * np, 1.f) : 0.f;
        if (nv == 0.f) { cl = 0.f; rl = 0.f; }
        s_c[tid] = cl; s_r[tid] = rl;
    }
    __syncthreads();

    if (tid == 0) {
        float ca = 0.f, ra = 0.f;
        for (int b2 = 0; b2 < B; ++b2) { ca += s_c[b2]; ra += s_r[b2]; }
        out[0] = ca / (float)B;
        out[1] = ra / (float)B;
    }
}

extern "C" void kernel_launch(void* const* d_in, const int* in_sizes, int n_in,
                              void* d_out, int out_size, void* d_ws, size_t ws_size,
                              hipStream_t stream) {
    const float* cls = (const float*)d_in[0];   // [B,A,C]
    const float* reg = (const float*)d_in[1];   // [B,A,4]
    const float* anc = (const float*)d_in[2];   // [1,A,4]
    const float* ann = (const float*)d_in[3];   // [B,M,5]
    const int A = in_sizes[2] / 4;
    const int B = in_sizes[3] / (M * 5);

    float* ws = (float*)d_ws;                             // accumulators
    unsigned char* tags = (unsigned char*)d_ws + TAG_OFF; // [B,A] tags

    // zero only the accumulator block (tags fully overwritten by focal_assign)
    hipMemsetAsync(d_ws, 0, TAG_OFF, stream);

    dim3 grid((A + 255) / 256, B);
    focal_assign<<<grid, dim3(256), 0, stream>>>(reg, anc, ann, tags, ws, A);
    focal_cls   <<<grid, dim3(256), 0, stream>>>(cls, tags, ws, A);
    focal_final <<<1,    dim3(256), 0, stream>>>(ws, ann, (float*)d_out, B);
}

// Round 13
// 136.068 us; speedup vs baseline: 2.5118x; 1.7023x over previous
//
#include <hip/hip_runtime.h>
#include <math.h>

#define FL_ALPHA 0.2f
#define FL_EPS   1e-8f

constexpr int C = 20;   // classes
constexpr int M = 32;   // max GT per image

// d_ws layout: part[(b*nblk + bx)*4 + {0,1,2}] = {cls_sum, reg_sum, num_pos}
// per block. Plain stores — NO atomics (R12 lesson: device-scope atomicAdd to
// 2 cache lines serializes at ~28 cyc each; 11K atomics == 135 us).
__global__ __launch_bounds__(256) void focal_main(
    const float* __restrict__ cls,   // [B,A,C]
    const float* __restrict__ reg,   // [B,A,4]
    const float* __restrict__ anc,   // [A,4]
    const float* __restrict__ ann,   // [B,M,5]
    float* __restrict__ part,
    int A)
{
    __shared__ float s_ann[M * 5];
    __shared__ float s_area[M];
    __shared__ float s_red[4 * 3];

    const int b   = blockIdx.y;
    const int tid = threadIdx.x;

    if (tid < M * 5) s_ann[tid] = ann[(size_t)b * M * 5 + tid];
    __syncthreads();
    if (tid < M) {
        const float gx1 = s_ann[tid*5+0], gy1 = s_ann[tid*5+1];
        const float gx2 = s_ann[tid*5+2], gy2 = s_ann[tid*5+3];
        s_area[tid] = (gx2 - gx1) * (gy2 - gy1);
    }
    __syncthreads();

    const int a = blockIdx.x * 256 + tid;

    float clsSum = 0.f, regSum = 0.f, posf = 0.f;

    if (a < A) {
        const float4 av = *(const float4*)(anc + (size_t)a * 4);
        const float aw  = av.z - av.x;
        const float ah  = av.w - av.y;
        const float acx = av.x + 0.5f * aw;
        const float acy = av.y + 0.5f * ah;
        const float area_a = aw * ah;

        // ---- IoU max / argmax over M GT (LDS broadcast reads) ----
        float iou_max = -2.0f;
        int   arg     = 0;
        #pragma unroll
        for (int j = 0; j < M; ++j) {
            const float gx1 = s_ann[j*5+0], gy1 = s_ann[j*5+1];
            const float gx2 = s_ann[j*5+2], gy2 = s_ann[j*5+3];
            const float gl  = s_ann[j*5+4];
            float iou = -1.0f;
            if (gl != -1.0f) {
                float iw = fminf(av.z, gx2) - fmaxf(av.x, gx1);
                iw = fmaxf(iw, 0.f);
                float ih = fminf(av.w, gy2) - fmaxf(av.y, gy1);
                ih = fmaxf(ih, 0.f);
                const float inter = iw * ih;
                const float ua = fmaxf(area_a + s_area[j] - inter, FL_EPS);
                iou = __fdividef(inter, ua);
            }
            if (iou > iou_max) { iou_max = iou; arg = j; }  // first-occurrence
        }

        const bool pos    = iou_max >= 0.5f;
        const bool ignore = (iou_max >= 0.4f) && !pos;
        const int  lbl    = (int)s_ann[arg*5+4];

        // ---- classification focal loss (skip ignore-band anchors) ----
        if (!ignore) {
            const float* cp = cls + ((size_t)b * A + a) * C;
            #pragma unroll
            for (int k = 0; k < C / 4; ++k) {
                const float4 v = *(const float4*)(cp + k * 4);
                const float pv[4] = {v.x, v.y, v.z, v.w};
                #pragma unroll
                for (int u = 0; u < 4; ++u) {
                    const int c = k * 4 + u;
                    float p = fminf(fmaxf(pv[u], FL_EPS), 1.0f - FL_EPS);
                    const float q  = 1.0f - p;
                    const bool t1  = pos && (c == lbl);
                    const float pe = t1 ? q : p;
                    const float po = t1 ? p : q;
                    const float w  = t1 ? FL_ALPHA : (1.0f - FL_ALPHA);
                    // pe^1.5 == pe*sqrt(pe) exactly (GAMMA = 1.5)
                    clsSum += w * pe * __builtin_amdgcn_sqrtf(pe) * (-__logf(po));
                }
            }
        }

        // ---- regression smooth-L1 (positives only) ----
        if (pos) {
            posf = 1.0f;
            const float gx1 = s_ann[arg*5+0], gy1 = s_ann[arg*5+1];
            const float gx2 = s_ann[arg*5+2], gy2 = s_ann[arg*5+3];
            const float gwr = gx2 - gx1, ghr = gy2 - gy1;
            const float gcx = gx1 + 0.5f * gwr, gcy = gy1 + 0.5f * ghr;
            const float gw  = fmaxf(gwr, 1.0f), gh = fmaxf(ghr, 1.0f);
            float rt[4];
            rt[0] = ((gcx - acx) / aw) / 0.1f;
            rt[1] = ((gcy - acy) / ah) / 0.1f;
            rt[2] = __logf(gw / aw) / 0.2f;
            rt[3] = __logf(gh / ah) / 0.2f;
            const float4 rv = *(const float4*)(reg + ((size_t)b * A + a) * 4);
            const float rr[4] = {rv.x, rv.y, rv.z, rv.w};
            #pragma unroll
            for (int u = 0; u < 4; ++u) {
                const float d = fabsf(rt[u] - rr[u]);
                regSum += (d <= (float)(1.0 / 9.0)) ? (4.5f * d * d)
                                                    : (d - (float)(0.5 / 9.0));
            }
        }
    }

    // ---- block reduce: wave shuffle -> cross-wave LDS -> ONE plain store ----
    #pragma unroll
    for (int off = 32; off > 0; off >>= 1) {
        clsSum += __shfl_down(clsSum, off, 64);
        regSum += __shfl_down(regSum, off, 64);
        posf   += __shfl_down(posf,   off, 64);
    }
    const int wave = tid >> 6;
    const int lane = tid & 63;
    if (lane == 0) {
        s_red[wave*3+0] = clsSum;
        s_red[wave*3+1] = regSum;
        s_red[wave*3+2] = posf;
    }
    __syncthreads();
    if (tid == 0) {
        float cs = 0.f, rs = 0.f, ps = 0.f;
        #pragma unroll
        for (int w2 = 0; w2 < 4; ++w2) {
            cs += s_red[w2*3+0];
            rs += s_red[w2*3+1];
            ps += s_red[w2*3+2];
        }
        const size_t slot = ((size_t)b * gridDim.x + blockIdx.x) * 4;
        *(float4*)(part + slot) = make_float4(cs, rs, ps, 0.f);
    }
}

// Tree-reduce the B x nblk partial triplets + final normalization.
// 1024 threads: 128 threads per image (B=8).
__global__ __launch_bounds__(1024) void focal_final(
    const float* __restrict__ part,
    const float* __restrict__ ann,
    float* __restrict__ out, int B, int nblk)
{
    __shared__ float s_sum[8][2][3];   // [image][wave-in-group][{cls,reg,pos}]
    __shared__ float s_f[256];
    __shared__ float s_c[8], s_r[8];

    const int tid = threadIdx.x;
    const int g   = tid >> 7;          // image 0..7
    const int i   = tid & 127;

    float cs = 0.f, rs = 0.f, ps = 0.f;
    if (g < B) {
        for (int bx = i; bx < nblk; bx += 128) {
            const float4 v = *(const float4*)(part + ((size_t)g * nblk + bx) * 4);
            cs += v.x; rs += v.y; ps += v.z;
        }
    }
    #pragma unroll
    for (int off = 32; off > 0; off >>= 1) {
        cs += __shfl_down(cs, off, 64);
        rs += __shfl_down(rs, off, 64);
        ps += __shfl_down(ps, off, 64);
    }
    const int lane = tid & 63;
    const int wv   = (tid >> 6) & 1;   // wave within the 128-thread group
    if (lane == 0 && g < 8) {
        s_sum[g][wv][0] = cs; s_sum[g][wv][1] = rs; s_sum[g][wv][2] = ps;
    }

    // GT validity flags in parallel (B*M = 256)
    if (tid < 256) {
        float f = 0.f;
        if (tid < B * M) {
            const int bb = tid >> 5, j = tid & 31;
            f = (ann[(size_t)bb * M * 5 + (size_t)j * 5 + 4] != -1.0f) ? 1.f : 0.f;
        }
        s_f[tid] = f;
    }
    __syncthreads();

    if (tid < B) {
        const float S  = s_sum[tid][0][0] + s_sum[tid][1][0];
        const float R  = s_sum[tid][0][1] + s_sum[tid][1][1];
        const float np = s_sum[tid][0][2] + s_sum[tid][1][2];
        float nv = 0.f;
        #pragma unroll
        for (int j = 0; j < M; ++j) nv += s_f[tid * M + j];
        float cl = S / fmaxf(np, 1.f);
        float rl = (np > 0.f) ? R / fmaxf(4.f * np, 1.f) : 0.f;
        if (nv == 0.f) { cl = 0.f; rl = 0.f; }
        s_c[tid] = cl; s_r[tid] = rl;
    }
    __syncthreads();

    if (tid == 0) {
        float ca = 0.f, ra = 0.f;
        for (int b2 = 0; b2 < B; ++b2) { ca += s_c[b2]; ra += s_r[b2]; }
        out[0] = ca / (float)B;
        out[1] = ra / (float)B;
    }
}

extern "C" void kernel_launch(void* const* d_in, const int* in_sizes, int n_in,
                              void* d_out, int out_size, void* d_ws, size_t ws_size,
                              hipStream_t stream) {
    const float* cls = (const float*)d_in[0];   // [B,A,C]
    const float* reg = (const float*)d_in[1];   // [B,A,4]
    const float* anc = (const float*)d_in[2];   // [1,A,4]
    const float* ann = (const float*)d_in[3];   // [B,M,5]
    const int A = in_sizes[2] / 4;
    const int B = in_sizes[3] / (M * 5);
    const int nblk = (A + 255) / 256;

    float* part = (float*)d_ws;   // B*nblk*4 floats (~60 KB); every slot is
                                  // written by focal_main, so no memset needed.

    dim3 grid(nblk, B);
    focal_main<<<grid, dim3(256), 0, stream>>>(cls, reg, anc, ann, part, A);
    focal_final<<<1, dim3(1024), 0, stream>>>(part, ann, (float*)d_out, B, nblk);
}